// Round 1
// baseline (249.508 us; speedup 1.0000x reference)
//
#include <hip/hip_runtime.h>
#include <stdint.h>

#define NSEL 300
#define BB 2
#define QQ 900
#define CC 91
#define NQC (QQ * CC)   // 81900
#define MH 128
#define MW 128
#define TGT 512

#define NBUCKET 4096
#define CAND_CAP 4096

// ---------------- Kernel 1: top-k + boxes/labels/uncertainty ----------------
__global__ __launch_bounds__(1024) void topk_kernel(
    const float* __restrict__ logits,    // [B,Q,C]
    const float* __restrict__ boxes_in,  // [B,Q,4]
    const float* __restrict__ logvars,   // [B,Q,4]
    const int*   __restrict__ tsizes,    // [B,2]
    float* __restrict__ out,             // full output buffer (float32)
    int*   __restrict__ sel)             // [B*NSEL] selected q indices
{
    __shared__ uint32_t hist[NBUCKET];
    __shared__ unsigned long long cand[CAND_CAP];
    __shared__ int s_count;
    __shared__ int s_cut;

    const int b   = blockIdx.x;
    const int tid = threadIdx.x;
    const float* lg = logits + (size_t)b * NQC;

    for (int i = tid; i < NBUCKET; i += 1024) hist[i] = 0u;
    if (tid == 0) s_count = 0;
    __syncthreads();

    // Pass 1: histogram of prob-key top bits. prob in (0,1] -> bits monotonic.
    for (int i = tid; i < NQC; i += 1024) {
        float x = lg[i];
        float p = 1.0f / (1.0f + expf(-x));
        uint32_t key = __float_as_uint(p);
        atomicAdd(&hist[key >> 18], 1u);
    }
    __syncthreads();

    if (tid == 0) {
        int acc = 0, cut = 0;
        for (int bkt = NBUCKET - 1; bkt >= 0; --bkt) {
            acc += (int)hist[bkt];
            if (acc >= NSEL) { cut = bkt; break; }
        }
        s_cut = cut;
    }
    __syncthreads();
    const uint32_t cut = (uint32_t)s_cut;

    // Pass 2: collect candidates (superset of the true top-300)
    for (int i = tid; i < NQC; i += 1024) {
        float x = lg[i];
        float p = 1.0f / (1.0f + expf(-x));
        uint32_t key = __float_as_uint(p);
        if ((key >> 18) >= cut) {
            int pos = atomicAdd(&s_count, 1);
            if (pos < CAND_CAP) {
                // composite: high = prob bits, low = ~index  (desc sort =>
                // higher prob first; equal prob => lower index first, like lax.top_k)
                cand[pos] = ((unsigned long long)key << 32) | (uint32_t)(~(uint32_t)i);
            }
        }
    }
    __syncthreads();

    int count = s_count;
    if (count > CAND_CAP) count = CAND_CAP;
    int P = 512;
    while (P < count) P <<= 1;
    for (int i = count + tid; i < P; i += 1024) cand[i] = 0ull;  // pads sort last
    __syncthreads();

    // Bitonic sort, descending
    for (int k = 2; k <= P; k <<= 1) {
        for (int j = k >> 1; j > 0; j >>= 1) {
            for (int i = tid; i < P; i += 1024) {
                int l = i ^ j;
                if (l > i) {
                    unsigned long long a = cand[i];
                    unsigned long long c2 = cand[l];
                    bool up = ((i & k) == 0);   // descending order
                    if ((a < c2) == up) { cand[i] = c2; cand[l] = a; }
                }
            }
            __syncthreads();
        }
    }

    // Epilogue: emit small outputs
    float* out_scores = out;                 // [B*NSEL]
    float* out_labels = out + 600;           // [B*NSEL]
    float* out_boxes  = out + 1200;          // [B*NSEL*4]
    float* out_unc    = out + 3600;          // [B*NSEL]

    if (tid < NSEL) {
        unsigned long long e = cand[tid];
        uint32_t key = (uint32_t)(e >> 32);
        uint32_t idx = ~((uint32_t)(e & 0xFFFFFFFFull));
        int q = (int)(idx / CC);
        int label = (int)(idx - (uint32_t)q * CC);
        int o = b * NSEL + tid;

        out_scores[o] = __uint_as_float(key);
        out_labels[o] = (float)label;

        const float* bx = boxes_in + ((size_t)(b * QQ + q)) * 4;
        float cx = bx[0], cy = bx[1], w = bx[2], h = bx[3];
        float hh = (float)tsizes[b * 2 + 0];
        float ww = (float)tsizes[b * 2 + 1];
        out_boxes[o * 4 + 0] = (cx - 0.5f * w) * ww;
        out_boxes[o * 4 + 1] = (cy - 0.5f * h) * hh;
        out_boxes[o * 4 + 2] = (cx + 0.5f * w) * ww;
        out_boxes[o * 4 + 3] = (cy + 0.5f * h) * hh;

        const float* gv = logvars + ((size_t)(b * QQ + q)) * 4;
        float s0 = gv[0] + gv[1];
        float s1 = s0 + gv[2];
        float s2 = s1 + gv[3];
        out_unc[o] = s2 * 0.25f;

        sel[o] = q;
    }
}

// ---------------- Kernel 2: bilinear upsample 128->512 + threshold ----------
// jax.image.resize bilinear (half-pixel): x_in = (x+0.5)/4 - 0.5 = x*0.25 - 0.375
// Edge normalization == weight-1 clamp. Vertical first, then horizontal,
// one rounding per op (no FMA) to match the reference contraction.
__global__ __launch_bounds__(256) void mask_kernel(
    const float* __restrict__ masks_in,  // [B,Q,128,128]
    const int*   __restrict__ sel,       // [B*NSEL]
    float* __restrict__ out_masks)       // [B*NSEL,512,512]
{
    const int m     = blockIdx.x;        // 0..599
    const int b     = m / NSEL;
    const int ytile = blockIdx.y;        // 0..3 -> 128 output rows each
    const int q     = sel[m];

    const float* src = masks_in + ((size_t)(b * QQ + q)) * (MH * MW);
    float* dst = out_masks + (size_t)m * (TGT * TGT);

    const int y0 = ytile * 128;
    int r_lo = (int)floorf((float)y0 * 0.25f - 0.375f);
    if (r_lo < 0) r_lo = 0;
    int r_hi = (int)floorf((float)(y0 + 127) * 0.25f - 0.375f) + 1;
    if (r_hi > MH - 1) r_hi = MH - 1;
    const int nrows = r_hi - r_lo + 1;   // <= 34

    __shared__ float S[34 * MW];
    for (int i = threadIdx.x; i < nrows * MW; i += 256)
        S[i] = src[(size_t)r_lo * MW + i];
    __syncthreads();

    const int x = threadIdx.x * 2;       // two consecutive output columns

    for (int yy = 0; yy < 128; ++yy) {
        const int y = y0 + yy;
        float yin = (float)y * 0.25f - 0.375f;   // exact in f32
        int r0 = (int)floorf(yin);
        float fy = yin - (float)r0;
        int r1 = r0 + 1;
        if (r0 < 0)          { r0 = 0; r1 = 0; fy = 0.0f; }
        else if (r1 > MH - 1){ r0 = MH - 1; r1 = MH - 1; fy = 0.0f; }
        const float wy0 = 1.0f - fy;
        const float wy1 = fy;
        const float* Ra = S + (size_t)(r0 - r_lo) * MW;
        const float* Rb = S + (size_t)(r1 - r_lo) * MW;

        float res[2];
        #pragma unroll
        for (int u = 0; u < 2; ++u) {
            const int xx = x + u;
            float xin = (float)xx * 0.25f - 0.375f;  // exact
            int c0 = (int)floorf(xin);
            float fx = xin - (float)c0;
            int c1 = c0 + 1;
            if (c0 < 0)           { c0 = 0; c1 = 0; fx = 0.0f; }
            else if (c1 > MW - 1) { c0 = MW - 1; c1 = MW - 1; fx = 0.0f; }
            // vertical combine (per-op rounding, ascending index order)
            float t0 = __fadd_rn(__fmul_rn(wy0, Ra[c0]), __fmul_rn(wy1, Rb[c0]));
            float t1 = __fadd_rn(__fmul_rn(wy0, Ra[c1]), __fmul_rn(wy1, Rb[c1]));
            // horizontal combine
            float v = __fadd_rn(__fmul_rn(1.0f - fx, t0), __fmul_rn(fx, t1));
            res[u] = (v > 0.0f) ? 1.0f : 0.0f;
        }
        *reinterpret_cast<float2*>(&dst[(size_t)y * TGT + x]) =
            make_float2(res[0], res[1]);
    }
}

extern "C" void kernel_launch(void* const* d_in, const int* in_sizes, int n_in,
                              void* d_out, int out_size, void* d_ws, size_t ws_size,
                              hipStream_t stream) {
    (void)in_sizes; (void)n_in; (void)out_size; (void)ws_size;

    const float* pred_logits  = (const float*)d_in[0];  // [2,900,91]
    const float* pred_boxes   = (const float*)d_in[1];  // [2,900,4]
    const float* pred_masks   = (const float*)d_in[2];  // [2,900,128,128]
    const float* pred_logvars = (const float*)d_in[3];  // [2,900,4]
    const int*   target_sizes = (const int*)d_in[4];    // [2,2]

    float* out = (float*)d_out;
    int*   sel = (int*)d_ws;                            // 600 ints

    hipLaunchKernelGGL(topk_kernel, dim3(BB), dim3(1024), 0, stream,
                       pred_logits, pred_boxes, pred_logvars, target_sizes,
                       out, sel);

    float* out_masks = out + 4200;  // after scores/labels/boxes/uncertainty
    hipLaunchKernelGGL(mask_kernel, dim3(BB * NSEL, 4), dim3(256), 0, stream,
                       pred_masks, sel, out_masks);
}